// Round 8
// baseline (1237.218 us; speedup 1.0000x reference)
//
#include <hip/hip_runtime.h>

// DepthFlowProjection (DAIN, fillhole=0) forward — LDS-privatized scatter.
// R8: ABLATION ROUND. R4/R6/R7 plateau at ~550-600us invariant to load
// width, pipeline depth, tile size, occupancy; VALU 10%, HBM 4%, bank
// conflicts 0. Ship 4 template variants as separate dispatches and read
// per-dispatch dur from rocprof:
//   M1 = loads only          M2 = loads + VALU/branches (atomics stubbed)
//   M3 = + real LDS atomics  M0 = full (validated output)
// M1-M3 write only into the leak buffer region, which is memset before M0.

constexpr int W  = 1920, H = 1080;
constexpr int HW = W * H;
constexpr int Sh = 20, Wt = 160, R = 24;
constexpr int TX = W / Wt, TY = H / Sh;     // 12, 54
constexpr int SW = Sh * Wt;                 // 3200 px per tile
constexpr float LEAK_THR = (float)(R - 1);  // 23.0f

#define KEEP(x)  asm volatile("" :: "v"(x))
#define KEEP4(a) asm volatile("" :: "v"((a).x), "v"((a).y), "v"((a).z), "v"((a).w))

template<int MODE>
__global__ __launch_bounds__(512, 8) void dfp_tile(
    const float* __restrict__ flow, const float* __restrict__ depth,
    float* __restrict__ leak,      // [B*HW] float4 cells (zeroed before M0)
    float* __restrict__ cnt_out,   // raw tile cnt, stride cnt_stride
    int cnt_stride,
    float* __restrict__ out, int B)
{
    __shared__ __align__(16) float acc[3 * SW];   // cnt, sx, sy (38.4 KB)
    const int tid  = threadIdx.x;
    const int lane = tid & 63;
    const int wid  = tid >> 6;

    int nwg  = gridDim.x;
    int orig = blockIdx.x;
    int blk  = ((nwg & 7) == 0) ? (orig & 7) * (nwg >> 3) + (orig >> 3) : orig;

    int b  = blk / (TX * TY);
    int t  = blk - b * (TX * TY);
    int ty = t / TX;
    int tx = t - ty * TX;
    const int Y0 = ty * Sh, X0 = tx * Wt;

    float4* accv = (float4*)acc;
    for (int i = tid; i < 3 * SW / 4; i += 512)
        accv[i] = make_float4(0.f, 0.f, 0.f, 0.f);
    __syncthreads();

    const float* fxp = flow + (size_t)b * 2 * HW;
    const float* fyp = fxp + HW;
    const float* dp  = depth + (size_t)b * HW;

    const int r0 = max(Y0 - R, 0), r1 = min(Y0 + Sh + R, H);
    const int c0 = max(X0 - R, 0), c1 = min(X0 + Wt + R, W);
    const int nlv = (c1 - c0) >> 2;      // # valid lanes (<= 52)
    const int ce  = c0 + (lane << 2);
    const int cl  = min(ce, c1 - 4);

    auto ldrow = [&](int r, float4& f4x, float4& f4y, float4& d4) {
        size_t p = (size_t)r * W + cl;
        f4x = *(const float4*)(fxp + p);
        f4y = *(const float4*)(fyp + p);
        d4  = *(const float4*)(dp  + p);
    };

    auto proc1 = [&](int row, int col, float fx, float fy, float dv) {
        float x2 = (float)col + fx;
        float y2 = (float)row + fy;
        if (!(x2 >= 0.f && y2 >= 0.f && x2 <= (float)(W - 1) && y2 <= (float)(H - 1)))
            return;
        int ixL = min(max((int)floorf(x2), 0), W - 1);
        int iyT = min(max((int)floorf(y2), 0), H - 1);
        int ixR = min(ixL + 1, W - 1);
        int iyB = min(iyT + 1, H - 1);
        float vx = -fx * dv, vy = -fy * dv;

        if (fabsf(fx) <= LEAK_THR && fabsf(fy) <= LEAK_THR) {
#define CORNER(iy, ix) do {                                              \
    if ((unsigned)((iy) - Y0) < (unsigned)Sh &&                          \
        (unsigned)((ix) - X0) < (unsigned)Wt) {                          \
        int o = ((iy) - Y0) * Wt + ((ix) - X0);                          \
        if constexpr (MODE == 2) {                                       \
            KEEP(o); KEEP(dv); KEEP(vx); KEEP(vy);                       \
        } else {                                                         \
            atomicAdd(&acc[o],          dv);                             \
            atomicAdd(&acc[o + SW],     vx);                             \
            atomicAdd(&acc[o + 2*SW],   vy);                             \
        }                                                                \
    } } while (0)
            CORNER(iyT, ixL); CORNER(iyT, ixR);
            CORNER(iyB, ixL); CORNER(iyB, ixR);
#undef CORNER
        } else if ((unsigned)(row - Y0) < (unsigned)Sh &&
                   (unsigned)(col - X0) < (unsigned)Wt) {
            if constexpr (MODE == 0) {
                size_t base = (size_t)b * HW * 4;
#define GCORNER(iy, ix) do {                                             \
    size_t o = base + (size_t)((iy) * W + (ix)) * 4;                     \
    atomicAdd(leak + o + 0, dv);                                         \
    atomicAdd(leak + o + 1, vx);                                         \
    atomicAdd(leak + o + 2, vy);                                         \
    } while (0)
                GCORNER(iyT, ixL); GCORNER(iyT, ixR);
                GCORNER(iyB, ixL); GCORNER(iyB, ixR);
#undef GCORNER
            } else {
                KEEP(dv); KEEP(vx); KEEP(vy);
                KEEP(iyT * W + ixL); KEEP(iyT * W + ixR);
                KEEP(iyB * W + ixL); KEEP(iyB * W + ixR);
            }
        }
    };

    auto proc4 = [&](int row, const float4& f4x, const float4& f4y, const float4& d4) {
        if constexpr (MODE == 1) {
            KEEP4(f4x); KEEP4(f4y); KEEP4(d4);
            return;
        }
        if (lane >= nlv) return;
        proc1(row, cl + 0, f4x.x, f4y.x, d4.x);
        proc1(row, cl + 1, f4x.y, f4y.y, d4.y);
        proc1(row, cl + 2, f4x.z, f4y.z, d4.z);
        proc1(row, cl + 3, f4x.w, f4y.w, d4.w);
    };

    // 2-deep software-pipelined row loop; named slots A/B
    int r = r0 + wid;
    float4 fxA, fyA, dA, fxB, fyB, dB;
    if (r     < r1) ldrow(r,     fxA, fyA, dA);
    if (r + 8 < r1) ldrow(r + 8, fxB, fyB, dB);
    while (r < r1) {
        if (r + 16 < r1) {
            float4 t1, t2, t3;
            ldrow(r + 16, t1, t2, t3);
            proc4(r, fxA, fyA, dA);
            fxA = t1; fyA = t2; dA = t3;
        } else {
            proc4(r, fxA, fyA, dA);
        }
        r += 8;
        if (r >= r1) break;
        if (r + 16 < r1) {
            float4 t1, t2, t3;
            ldrow(r + 16, t1, t2, t3);
            proc4(r, fxB, fyB, dB);
            fxB = t1; fyB = t2; dB = t3;
        } else {
            proc4(r, fxB, fyB, dB);
        }
        r += 8;
    }
    __syncthreads();

    // flush RAW sums (MODE!=0: host passes out/cnt_out inside leak scratch)
    float* outx = out + (size_t)b * 2 * HW;
    float* outy = outx + HW;
    for (int i = tid; i < SW; i += 512) {
        int ly = i / Wt;
        int lx = i - ly * Wt;
        int gp = (Y0 + ly) * W + (X0 + lx);
        outx[gp] = acc[i + SW];
        outy[gp] = acc[i + 2 * SW];
        cnt_out[(size_t)((size_t)b * HW + gp) * cnt_stride] = acc[i];
    }
}

// Kernel 2: combine tile sums + leak, normalize (stream-ordered -> race-free)
__global__ void dfp_finalize(const float4* __restrict__ leak,
                             const float* __restrict__ cnt_in,
                             int cnt_stride,
                             float* __restrict__ out, int B)
{
    const long total = (long)B * HW;
    long idx = (long)blockIdx.x * blockDim.x + threadIdx.x;
    if (idx >= total) return;
    int b = (int)(idx / HW);
    int p = (int)(idx - (long)b * HW);

    float4 lk = leak[idx];
    float cnt = cnt_in[(size_t)idx * cnt_stride] + lk.x;
    float den = (cnt > 0.f) ? cnt : 1.f;

    size_t o = (size_t)b * 2 * HW + p;
    out[o]      = (out[o]      + lk.y) / den;
    out[o + HW] = (out[o + HW] + lk.z) / den;
}

// ---------------- fallback (round-1) path if ws is too small ----------------

__global__ void dfp_scatter(const float* __restrict__ flow,
                            const float* __restrict__ depth,
                            float* __restrict__ out,
                            float* __restrict__ count, int B)
{
    const long total = (long)B * HW;
    long idx = (long)blockIdx.x * blockDim.x + threadIdx.x;
    if (idx >= total) return;
    int b = (int)(idx / HW);
    int p = (int)(idx - (long)b * HW);
    int y = p / W;
    int x = p - y * W;
    const float* f = flow + (size_t)b * 2 * HW;
    float fx = f[p], fy = f[HW + p], d = depth[idx];
    float x2 = (float)x + fx, y2 = (float)y + fy;
    if (!(x2 >= 0.f && y2 >= 0.f && x2 <= (float)(W - 1) && y2 <= (float)(H - 1)))
        return;
    int ixL = min(max((int)floorf(x2), 0), W - 1);
    int iyT = min(max((int)floorf(y2), 0), H - 1);
    int ixR = min(ixL + 1, W - 1), iyB = min(iyT + 1, H - 1);
    float vx = -fx * d, vy = -fy * d;
    float* cnt_b  = count + (size_t)b * HW;
    float* outx_b = out + (size_t)b * 2 * HW;
    float* outy_b = outx_b + HW;
    int o00 = iyT * W + ixL, o01 = iyT * W + ixR;
    int o10 = iyB * W + ixL, o11 = iyB * W + ixR;
    atomicAdd(&cnt_b[o00], d);   atomicAdd(&cnt_b[o01], d);
    atomicAdd(&cnt_b[o10], d);   atomicAdd(&cnt_b[o11], d);
    atomicAdd(&outx_b[o00], vx); atomicAdd(&outx_b[o01], vx);
    atomicAdd(&outx_b[o10], vx); atomicAdd(&outx_b[o11], vx);
    atomicAdd(&outy_b[o00], vy); atomicAdd(&outy_b[o01], vy);
    atomicAdd(&outy_b[o10], vy); atomicAdd(&outy_b[o11], vy);
}

__global__ void dfp_normalize(float* __restrict__ out,
                              const float* __restrict__ count, int B)
{
    const long total = (long)B * HW;
    long idx = (long)blockIdx.x * blockDim.x + threadIdx.x;
    if (idx >= total) return;
    int b = (int)(idx / HW);
    int p = (int)(idx - (long)b * HW);
    float c = count[idx];
    float den = (c > 0.f) ? c : 1.f;
    size_t o = (size_t)b * 2 * HW + p;
    out[o]      = out[o] / den;
    out[o + HW] = out[o + HW] / den;
}

extern "C" void kernel_launch(void* const* d_in, const int* in_sizes, int n_in,
                              void* d_out, int out_size, void* d_ws, size_t ws_size,
                              hipStream_t stream) {
    const float* flow  = (const float*)d_in[0];
    const float* depth = (const float*)d_in[1];
    float* out = (float*)d_out;

    const int B = in_sizes[1] / HW;
    const long total = (long)B * HW;

    const size_t cell_bytes  = (size_t)total * 4 * sizeof(float);
    const size_t plane_bytes = (size_t)total * sizeof(float);

    const int fin_threads = 256;
    const int fin_blocks  = (int)((total + fin_threads - 1) / fin_threads);
    const int grid = B * TX * TY;

    if (ws_size >= cell_bytes + plane_bytes) {
        float* leak = (float*)d_ws;
        float* cnt  = leak + (size_t)total * 4;

        // --- ablation dispatches (scribble only into leak region; memset follows)
        dfp_tile<1><<<grid, 512, 0, stream>>>(flow, depth, leak, leak, 1, leak, B);
        dfp_tile<2><<<grid, 512, 0, stream>>>(flow, depth, leak, leak, 1, leak, B);
        dfp_tile<3><<<grid, 512, 0, stream>>>(flow, depth, leak, leak, 1, leak, B);

        // --- real path
        hipMemsetAsync(d_ws, 0, cell_bytes, stream);
        dfp_tile<0><<<grid, 512, 0, stream>>>(flow, depth, leak, cnt, 1, out, B);
        dfp_finalize<<<fin_blocks, fin_threads, 0, stream>>>((const float4*)leak, cnt, 1, out, B);
    } else if (ws_size >= cell_bytes) {
        float* leak = (float*)d_ws;
        hipMemsetAsync(d_ws, 0, cell_bytes, stream);
        dfp_tile<0><<<grid, 512, 0, stream>>>(flow, depth, leak, leak + 3, 4, out, B);
        dfp_finalize<<<fin_blocks, fin_threads, 0, stream>>>((const float4*)leak, leak + 3, 4, out, B);
    } else {
        const int threads = 256;
        const int blocks = (int)((total + threads - 1) / threads);
        float* cnt = (float*)d_ws;
        hipMemsetAsync(d_out, 0, (size_t)total * 2 * sizeof(float), stream);
        hipMemsetAsync(d_ws, 0, plane_bytes, stream);
        dfp_scatter<<<blocks, threads, 0, stream>>>(flow, depth, out, cnt, B);
        dfp_normalize<<<blocks, threads, 0, stream>>>(out, cnt, B);
    }
}

// Round 9
// 215.715 us; speedup vs baseline: 5.7354x; 5.7354x over previous
//
#include <hip/hip_runtime.h>

// DepthFlowProjection (DAIN, fillhole=0) forward — LDS-privatized scatter.
// R9: box-splat decomposition. R8 ablation: ~490/543us of the tile kernel is
// the LDS-atomic path, rate-limited per ds_add INSTRUCTION (~40cy), not by
// banks/lanes. Since the reference adds the SAME (d,vx,vy) to all 4 corners,
// accumulate only the base corner S[iyT][ixL] (3 ds_adds/pixel instead of
// 12) and produce out[y][x] = 2x2 window sum of S in the flush (pure
// conflict-free ds_reads). Exact-integer edge landings (x2==W-1 or y2==H-1,
// where the reference double-adds clamped corners) go through the leak path
// which reproduces reference multiplicity.

constexpr int W  = 1920, H = 1080;
constexpr int HW = W * H;
constexpr int Sh = 20, Wt = 128, R = 24;
constexpr int TX = W / Wt, TY = H / Sh;     // 15, 54
constexpr int SW = Sh * Wt;                 // 2560 outputs per tile
constexpr int SP = (Sh + 1) * (Wt + 1);     // 2709 S-cells per plane (stride 129)
constexpr int ACCN = (3 * SP + 3) & ~3;     // 8128 floats (32.5 KB)
constexpr float LEAK_THR = (float)(R - 1);  // 23.0f

__global__ __launch_bounds__(512, 8) void dfp_tile(
    const float* __restrict__ flow, const float* __restrict__ depth,
    float* __restrict__ leak,      // [B*HW] float4 cells, zeroed
    float* __restrict__ cnt_out,   // raw tile cnt, stride cnt_stride
    int cnt_stride,
    float* __restrict__ out, int B)
{
    __shared__ __align__(16) float acc[ACCN];   // S planes: cnt, sx, sy
    const int tid  = threadIdx.x;
    const int lane = tid & 63;
    const int wid  = tid >> 6;

    // XCD-aware swizzle (grid = 3240, mod 8 == 0 -> simple bijective form)
    int nwg  = gridDim.x;
    int orig = blockIdx.x;
    int blk  = ((nwg & 7) == 0) ? (orig & 7) * (nwg >> 3) + (orig >> 3) : orig;

    int b  = blk / (TX * TY);
    int t  = blk - b * (TX * TY);
    int ty = t / TX;
    int tx = t - ty * TX;
    const int Y0 = ty * Sh, X0 = tx * Wt;

    float4* accv = (float4*)acc;
    for (int i = tid; i < ACCN / 4; i += 512)
        accv[i] = make_float4(0.f, 0.f, 0.f, 0.f);
    __syncthreads();

    const float* fxp = flow + (size_t)b * 2 * HW;
    const float* fyp = fxp + HW;
    const float* dp  = depth + (size_t)b * HW;

    const int r0 = max(Y0 - R, 0), r1 = min(Y0 + Sh + R, H);
    const int c0 = max(X0 - R, 0), c1 = min(X0 + Wt + R, W);
    // c1-c0 is a multiple of 4 (X0 mult of 128, R=24, W=1920)
    const int nlv = (c1 - c0) >> 2;      // # valid lanes (<= 44)
    const int ce  = c0 + (lane << 2);
    const int cl  = min(ce, c1 - 4);

    auto ldrow = [&](int r, float4& f4x, float4& f4y, float4& d4) {
        size_t p = (size_t)r * W + cl;
        f4x = *(const float4*)(fxp + p);
        f4y = *(const float4*)(fyp + p);
        d4  = *(const float4*)(dp  + p);
    };

    auto proc1 = [&](int row, int col, float fx, float fy, float dv) {
        float x2 = (float)col + fx;
        float y2 = (float)row + fy;
        if (!(x2 >= 0.f && y2 >= 0.f && x2 <= (float)(W - 1) && y2 <= (float)(H - 1)))
            return;
        int ixL = (int)floorf(x2);    // valid => in [0, W-1]
        int iyT = (int)floorf(y2);    // valid => in [0, H-1]
        float vx = -fx * dv, vy = -fy * dv;
        bool small = (fabsf(fx) <= LEAK_THR) && (fabsf(fy) <= LEAK_THR);
        bool dup   = (ixL >= W - 1) | (iyT >= H - 1);  // clamped-corner dup case

        if (small && !dup) {
            // base-corner accumulate: S rows [Y0-1, Y0+Sh-1], cols [X0-1, X0+Wt-1]
            int a = iyT - Y0 + 1;
            int c = ixL - X0 + 1;
            if ((unsigned)a < (unsigned)(Sh + 1) && (unsigned)c < (unsigned)(Wt + 1)) {
                int o = a * (Wt + 1) + c;
                atomicAdd(&acc[o],          dv);
                atomicAdd(&acc[o + SP],     vx);
                atomicAdd(&acc[o + 2*SP],   vy);
            }
        } else if ((unsigned)(row - Y0) < (unsigned)Sh &&
                   (unsigned)(col - X0) < (unsigned)Wt) {
            // big-flow or edge-dup pixel: handled once by its source-owning
            // tile via global atomics, reference-style 4 clamped corners.
            int ixR = min(ixL + 1, W - 1);
            int iyB = min(iyT + 1, H - 1);
            size_t base = (size_t)b * HW * 4;
#define GCORNER(iy, ix) do {                                             \
    size_t o = base + (size_t)((iy) * W + (ix)) * 4;                     \
    atomicAdd(leak + o + 0, dv);                                         \
    atomicAdd(leak + o + 1, vx);                                         \
    atomicAdd(leak + o + 2, vy);                                         \
    } while (0)
            GCORNER(iyT, ixL); GCORNER(iyT, ixR);
            GCORNER(iyB, ixL); GCORNER(iyB, ixR);
#undef GCORNER
        }
    };

    auto proc4 = [&](int row, const float4& f4x, const float4& f4y, const float4& d4) {
        if (lane >= nlv) return;
        proc1(row, cl + 0, f4x.x, f4y.x, d4.x);
        proc1(row, cl + 1, f4x.y, f4y.y, d4.y);
        proc1(row, cl + 2, f4x.z, f4y.z, d4.z);
        proc1(row, cl + 3, f4x.w, f4y.w, d4.w);
    };

    // 2-deep software-pipelined row loop; named slots A/B
    int r = r0 + wid;
    float4 fxA, fyA, dA, fxB, fyB, dB;
    if (r     < r1) ldrow(r,     fxA, fyA, dA);
    if (r + 8 < r1) ldrow(r + 8, fxB, fyB, dB);
    while (r < r1) {
        if (r + 16 < r1) {
            float4 t1, t2, t3;
            ldrow(r + 16, t1, t2, t3);
            proc4(r, fxA, fyA, dA);
            fxA = t1; fyA = t2; dA = t3;
        } else {
            proc4(r, fxA, fyA, dA);
        }
        r += 8;
        if (r >= r1) break;
        if (r + 16 < r1) {
            float4 t1, t2, t3;
            ldrow(r + 16, t1, t2, t3);
            proc4(r, fxB, fyB, dB);
            fxB = t1; fyB = t2; dB = t3;
        } else {
            proc4(r, fxB, fyB, dB);
        }
        r += 8;
    }
    __syncthreads();

    // flush: 2x2 window sum of S -> raw output sums (exclusive ownership)
    float* outx = out + (size_t)b * 2 * HW;
    float* outy = outx + HW;
    for (int i = tid; i < SW; i += 512) {
        int ly = i >> 7;            // Wt = 128
        int lx = i & 127;
        int o  = ly * (Wt + 1) + lx;
        float cnt = acc[o]        + acc[o + 1]
                  + acc[o + Wt+1] + acc[o + Wt+2];
        float sx  = acc[SP + o]        + acc[SP + o + 1]
                  + acc[SP + o + Wt+1] + acc[SP + o + Wt+2];
        float sy  = acc[2*SP + o]        + acc[2*SP + o + 1]
                  + acc[2*SP + o + Wt+1] + acc[2*SP + o + Wt+2];
        int gp = (Y0 + ly) * W + (X0 + lx);
        outx[gp] = sx;
        outy[gp] = sy;
        cnt_out[(size_t)((size_t)b * HW + gp) * cnt_stride] = cnt;
    }
}

// Kernel 2: combine tile sums + leak, normalize (stream-ordered -> race-free)
__global__ void dfp_finalize(const float4* __restrict__ leak,
                             const float* __restrict__ cnt_in,
                             int cnt_stride,
                             float* __restrict__ out, int B)
{
    const long total = (long)B * HW;
    long idx = (long)blockIdx.x * blockDim.x + threadIdx.x;
    if (idx >= total) return;
    int b = (int)(idx / HW);
    int p = (int)(idx - (long)b * HW);

    float4 lk = leak[idx];
    float cnt = cnt_in[(size_t)idx * cnt_stride] + lk.x;
    float den = (cnt > 0.f) ? cnt : 1.f;

    size_t o = (size_t)b * 2 * HW + p;
    out[o]      = (out[o]      + lk.y) / den;
    out[o + HW] = (out[o + HW] + lk.z) / den;
}

// ---------------- fallback (round-1) path if ws is too small ----------------

__global__ void dfp_scatter(const float* __restrict__ flow,
                            const float* __restrict__ depth,
                            float* __restrict__ out,
                            float* __restrict__ count, int B)
{
    const long total = (long)B * HW;
    long idx = (long)blockIdx.x * blockDim.x + threadIdx.x;
    if (idx >= total) return;
    int b = (int)(idx / HW);
    int p = (int)(idx - (long)b * HW);
    int y = p / W;
    int x = p - y * W;
    const float* f = flow + (size_t)b * 2 * HW;
    float fx = f[p], fy = f[HW + p], d = depth[idx];
    float x2 = (float)x + fx, y2 = (float)y + fy;
    if (!(x2 >= 0.f && y2 >= 0.f && x2 <= (float)(W - 1) && y2 <= (float)(H - 1)))
        return;
    int ixL = min(max((int)floorf(x2), 0), W - 1);
    int iyT = min(max((int)floorf(y2), 0), H - 1);
    int ixR = min(ixL + 1, W - 1), iyB = min(iyT + 1, H - 1);
    float vx = -fx * d, vy = -fy * d;
    float* cnt_b  = count + (size_t)b * HW;
    float* outx_b = out + (size_t)b * 2 * HW;
    float* outy_b = outx_b + HW;
    int o00 = iyT * W + ixL, o01 = iyT * W + ixR;
    int o10 = iyB * W + ixL, o11 = iyB * W + ixR;
    atomicAdd(&cnt_b[o00], d);   atomicAdd(&cnt_b[o01], d);
    atomicAdd(&cnt_b[o10], d);   atomicAdd(&cnt_b[o11], d);
    atomicAdd(&outx_b[o00], vx); atomicAdd(&outx_b[o01], vx);
    atomicAdd(&outx_b[o10], vx); atomicAdd(&outx_b[o11], vx);
    atomicAdd(&outy_b[o00], vy); atomicAdd(&outy_b[o01], vy);
    atomicAdd(&outy_b[o10], vy); atomicAdd(&outy_b[o11], vy);
}

__global__ void dfp_normalize(float* __restrict__ out,
                              const float* __restrict__ count, int B)
{
    const long total = (long)B * HW;
    long idx = (long)blockIdx.x * blockDim.x + threadIdx.x;
    if (idx >= total) return;
    int b = (int)(idx / HW);
    int p = (int)(idx - (long)b * HW);
    float c = count[idx];
    float den = (c > 0.f) ? c : 1.f;
    size_t o = (size_t)b * 2 * HW + p;
    out[o]      = out[o] / den;
    out[o + HW] = out[o + HW] / den;
}

extern "C" void kernel_launch(void* const* d_in, const int* in_sizes, int n_in,
                              void* d_out, int out_size, void* d_ws, size_t ws_size,
                              hipStream_t stream) {
    const float* flow  = (const float*)d_in[0];
    const float* depth = (const float*)d_in[1];
    float* out = (float*)d_out;

    const int B = in_sizes[1] / HW;
    const long total = (long)B * HW;

    const size_t cell_bytes  = (size_t)total * 4 * sizeof(float);
    const size_t plane_bytes = (size_t)total * sizeof(float);

    const int fin_threads = 256;
    const int fin_blocks  = (int)((total + fin_threads - 1) / fin_threads);
    const int grid = B * TX * TY;

    if (ws_size >= cell_bytes + plane_bytes) {
        float* leak = (float*)d_ws;
        float* cnt  = leak + (size_t)total * 4;
        hipMemsetAsync(d_ws, 0, cell_bytes, stream);
        dfp_tile<<<grid, 512, 0, stream>>>(flow, depth, leak, cnt, 1, out, B);
        dfp_finalize<<<fin_blocks, fin_threads, 0, stream>>>((const float4*)leak, cnt, 1, out, B);
    } else if (ws_size >= cell_bytes) {
        float* leak = (float*)d_ws;
        hipMemsetAsync(d_ws, 0, cell_bytes, stream);
        dfp_tile<<<grid, 512, 0, stream>>>(flow, depth, leak, leak + 3, 4, out, B);
        dfp_finalize<<<fin_blocks, fin_threads, 0, stream>>>((const float4*)leak, leak + 3, 4, out, B);
    } else {
        const int threads = 256;
        const int blocks = (int)((total + threads - 1) / threads);
        float* cnt = (float*)d_ws;
        hipMemsetAsync(d_out, 0, (size_t)total * 2 * sizeof(float), stream);
        hipMemsetAsync(d_ws, 0, plane_bytes, stream);
        dfp_scatter<<<blocks, threads, 0, stream>>>(flow, depth, out, cnt, B);
        dfp_normalize<<<blocks, threads, 0, stream>>>(out, cnt, B);
    }
}